// Round 14
// baseline (457.732 us; speedup 1.0000x reference)
//
#include <hip/hip_runtime.h>
#include <hip/hip_bf16.h>

#define M_DIM 16384
#define N_DIM 4096
#define K_DIM 4096
#define FP8_MAX 448.0f

#define BM 128
#define BN 256
#define NK64 (K_DIM / 64)   // 64 k64-blocks = K-tiles
#define BUFB 24576           // 8KB A + 16KB B per K-tile buffer

typedef float f32x16 __attribute__((ext_vector_type(16)));
typedef int i32x4 __attribute__((ext_vector_type(4)));
typedef int i32x8 __attribute__((ext_vector_type(8)));

// Packed fp8 operand layout (A and B identical), matched to the
// mfma_scale_f32_32x32x64_f8f6f4 fragment: lane l holds
//   row = row32*32 + (l&31),  k = k64*64 + (l>>5)*32 + h*16 + j  (h=0,1; j=0..15)
// stored as [row32-block][k64-block][h][lane][16B]  (block = 2048 B).
// GEMM (this round): TLP-overlap design. 128x256 tile, 8 waves, wave tile
// 64x64 (acc = 64 AGPR -> ~116 regs -> 4 waves/SIMD), LDS 3 x 24KB (depth-2)
// -> TWO blocks resident per CU with independent barriers: when one block
// drains its gate, the other's waves feed the MFMA pipe (m114 overlap).
// Step: gate(vmcnt3+lgkm0) -> bar -> 8 ds_reads(kt) + stage(kt+2) ->
// lgkm0 -> 4 MFMA. scales = 1.0 e8m0 -> bit-identical to plain fp8 math.

// ---------------- init ----------------
__global__ void init_amax_kernel(unsigned* amax) {
    if (threadIdx.x < 2) amax[threadIdx.x] = 0u;
}

// ---------------- fused amax reduction (x then w) ----------------
__global__ void amax2_kernel(const float* __restrict__ x,
                             const float* __restrict__ w,
                             unsigned* __restrict__ amax) {
    const float* p;
    long n4;
    unsigned* out;
    long bid, nb;
    if (blockIdx.x < 2048) {
        p = x; n4 = (long)M_DIM * K_DIM / 4; out = amax + 0;
        bid = blockIdx.x; nb = 2048;
    } else {
        p = w; n4 = (long)K_DIM * N_DIM / 4; out = amax + 1;
        bid = blockIdx.x - 2048; nb = 1024;
    }
    float m = 0.f;
    const float4* p4 = (const float4*)p;
    for (long i = bid * blockDim.x + threadIdx.x; i < n4; i += nb * blockDim.x) {
        float4 v = p4[i];
        m = fmaxf(m, fmaxf(fmaxf(fabsf(v.x), fabsf(v.y)),
                           fmaxf(fabsf(v.z), fabsf(v.w))));
    }
#pragma unroll
    for (int off = 32; off > 0; off >>= 1)
        m = fmaxf(m, __shfl_down(m, off));
    __shared__ float smax[4];
    int lane = threadIdx.x & 63, wid = threadIdx.x >> 6;
    if (lane == 0) smax[wid] = m;
    __syncthreads();
    if (threadIdx.x == 0) {
        float bm = fmaxf(fmaxf(smax[0], smax[1]), fmaxf(smax[2], smax[3]));
        atomicMax(out, __float_as_uint(bm));  // positive floats: bit order == value order
    }
}

__device__ __forceinline__ unsigned pack4(float4 v, float s) {
    float a = fminf(fmaxf(v.x * s, -FP8_MAX), FP8_MAX);
    float b = fminf(fmaxf(v.y * s, -FP8_MAX), FP8_MAX);
    float c = fminf(fmaxf(v.z * s, -FP8_MAX), FP8_MAX);
    float d = fminf(fmaxf(v.w * s, -FP8_MAX), FP8_MAX);
    int p = 0;
    p = __builtin_amdgcn_cvt_pk_fp8_f32(a, b, p, false);
    p = __builtin_amdgcn_cvt_pk_fp8_f32(c, d, p, true);
    return (unsigned)p;
}

// -------- fused quantize: blocks 0..511 -> x ; 512..4607 -> weight --------
__global__ void quant_kernel(const float* __restrict__ x,
                             const float* __restrict__ w,
                             unsigned char* __restrict__ qa,
                             unsigned char* __restrict__ qw,
                             const unsigned* __restrict__ amax) {
    __shared__ unsigned tile[64][17];     // used by the weight path only
    int t = threadIdx.x;
    if (blockIdx.x < 512) {
        // ---- x path: (M,K) fp32 -> packed fp8 ----
        float scale = FP8_MAX / fmaxf(__uint_as_float(amax[0]), 1e-12f);
        int m32 = blockIdx.x;             // 0..511 (M/32)
        int lane = t & 63;
        int g = t >> 6;                   // 0..3: k64 sub-block per iteration
        int m = m32 * 32 + (lane & 31);
        int kh = lane >> 5;               // k-half of the 64-wide K block
        const float* rp = x + (long)m * K_DIM;
        unsigned char* ob = qa + (long)m32 * NK64 * 2048;
#pragma unroll
        for (int it = 0; it < 16; ++it) { // 64 k64-blocks, 4 per iter
            int k64 = it * 4 + g;
            int kb = k64 * 64 + kh * 32;
            float4 v0 = *(const float4*)&rp[kb];
            float4 v1 = *(const float4*)&rp[kb + 4];
            float4 v2 = *(const float4*)&rp[kb + 8];
            float4 v3 = *(const float4*)&rp[kb + 12];
            float4 v4 = *(const float4*)&rp[kb + 16];
            float4 v5 = *(const float4*)&rp[kb + 20];
            float4 v6 = *(const float4*)&rp[kb + 24];
            float4 v7 = *(const float4*)&rp[kb + 28];
            uint4 o0, o1;
            o0.x = pack4(v0, scale); o0.y = pack4(v1, scale);
            o0.z = pack4(v2, scale); o0.w = pack4(v3, scale);
            o1.x = pack4(v4, scale); o1.y = pack4(v5, scale);
            o1.z = pack4(v6, scale); o1.w = pack4(v7, scale);
            *(uint4*)&ob[(long)k64 * 2048 + lane * 16] = o0;          // h=0
            *(uint4*)&ob[(long)k64 * 2048 + 1024 + lane * 16] = o1;   // h=1
        }
    } else {
        // ---- weight path: (K,N) -> packed fp8 (N-major) ----
        float scale = FP8_MAX / fmaxf(__uint_as_float(amax[1]), 1e-12f);
        int b = blockIdx.x - 512;         // 4096 = (K/64) * (N/64)
        int bk = b & 63, bn = b >> 6;
        int k0 = bk * 64, n0 = bn * 64;
#pragma unroll
        for (int pass = 0; pass < 4; ++pass) {
            int idx = pass * 256 + t;     // 64 k x 16 words
            int k = idx >> 4, nw = idx & 15;
            float4 v = *(const float4*)&w[(long)(k0 + k) * N_DIM + n0 + nw * 4];
            tile[k][nw] = pack4(v, scale);
        }
        __syncthreads();
        int lane = t & 63, g = t >> 6;
        int n32 = g >> 1, h = g & 1;      // 2 n32-blocks x 2 halves
        int nl = n32 * 32 + (lane & 31);
        int word = nl >> 2, sh = (nl & 3) * 8;
        int kb = (lane >> 5) * 32 + h * 16;
        uint4 o;
        unsigned* ow = (unsigned*)&o;
#pragma unroll
        for (int wd = 0; wd < 4; ++wd) {
            unsigned acc = 0;
#pragma unroll
            for (int j = 0; j < 4; ++j)
                acc |= ((tile[kb + wd * 4 + j][word] >> sh) & 0xffu) << (8 * j);
            ow[wd] = acc;
        }
        long gn32 = (long)(n0 >> 5) + n32;
        *(uint4*)&qw[(gn32 * NK64 + bk) * 2048 + h * 1024 + lane * 16] = o;
    }
}

// ---------------- MX-fp8 GEMM, TLP-overlap (2 blocks/CU, 4 waves/SIMD) ----------------
__device__ __forceinline__ void stage_q(const unsigned char* __restrict__ Aseg,
                                        const unsigned char* __restrict__ Bseg,
                                        unsigned char* stbuf, int tid, int kt) {
#pragma unroll
    for (int r = 0; r < 3; ++r) {
        int c = r * 512 + tid;            // 0..1535: A chunks 0..511, B 512..1535
        const unsigned char* src;
        if (c < 512)
            src = Aseg + ((long)(c >> 7) * NK64 + kt) * 2048 + (c & 127) * 16;
        else
            src = Bseg + ((long)((c - 512) >> 7) * NK64 + kt) * 2048 + (c & 127) * 16;
        __builtin_amdgcn_global_load_lds(
            (const __attribute__((address_space(1))) void*)src,
            (__attribute__((address_space(3))) void*)(stbuf + c * 16), 16, 0, 0);
    }
}

__device__ __forceinline__ i32x8 comb(i32x4 lo, i32x4 hi) {
    return __builtin_shufflevector(lo, hi, 0, 1, 2, 3, 4, 5, 6, 7);
}

#define SB() __builtin_amdgcn_sched_barrier(0)

// One K-tile step. Gate -> barrier -> read frags(kt) + stage(kt+2) ->
// lgkm drain -> 4 MFMA. Overlap comes from the OTHER resident block.
template <int VW, bool STG>
__device__ __forceinline__ void tile_step(
    unsigned char* sbase, const unsigned char* __restrict__ Aseg,
    const unsigned char* __restrict__ Bseg, int kt, int tid, int lane,
    int wm, int wn, f32x16 (&acc)[2][2]) {
    // gate: stage(kt) landed (own; steady outstanding 6 -> vmcnt(3) drains
    // stage(kt)); own prior ds_reads drained; barrier -> cross-wave visible.
    if constexpr (VW == 3)
        asm volatile("s_waitcnt vmcnt(3) lgkmcnt(0)" ::: "memory");
    else
        asm volatile("s_waitcnt vmcnt(0) lgkmcnt(0)" ::: "memory");
    SB();
    __builtin_amdgcn_s_barrier();
    SB();

    const unsigned char* buf = sbase + (size_t)(kt % 3) * BUFB;
    const unsigned char* Al = buf + (wm * 2) * 2048 + lane * 16;          // 2 row32
    const unsigned char* Bl = buf + 8192 + (wn * 2) * 2048 + lane * 16;   // 2 col32

    i32x4 a[2][2], bb[2][2];
#pragma unroll
    for (int i = 0; i < 2; ++i) {
        a[i][0] = *(const i32x4*)(Al + i * 2048);
        a[i][1] = *(const i32x4*)(Al + i * 2048 + 1024);
    }
#pragma unroll
    for (int j = 0; j < 2; ++j) {
        bb[j][0] = *(const i32x4*)(Bl + j * 2048);
        bb[j][1] = *(const i32x4*)(Bl + j * 2048 + 1024);
    }
    if constexpr (STG)
        stage_q(Aseg, Bseg, sbase + (size_t)((kt + 2) % 3) * BUFB, tid, kt + 2);
    SB();
    asm volatile("s_waitcnt lgkmcnt(0)" ::: "memory");
    SB();
    __builtin_amdgcn_s_setprio(1);
#pragma unroll
    for (int i = 0; i < 2; ++i)
#pragma unroll
        for (int j = 0; j < 2; ++j)
            acc[i][j] = __builtin_amdgcn_mfma_scale_f32_32x32x64_f8f6f4(
                comb(a[i][0], a[i][1]), comb(bb[j][0], bb[j][1]), acc[i][j],
                0, 0, 0, 0x7f7f7f7f, 0, 0x7f7f7f7f);
    __builtin_amdgcn_s_setprio(0);
}

__global__ __launch_bounds__(512, 4) void gemm_fp8_kernel(
    const unsigned char* __restrict__ qa, const unsigned char* __restrict__ qw,
    float* __restrict__ out, const unsigned* __restrict__ amax) {
    __shared__ unsigned char lds[3][BUFB];   // 72 KB -> 2 blocks/CU

    // XCD-bijective swizzle (nwg = 2048, divisible by 8)
    int b = blockIdx.x;
    int swz = (b & 7) * 256 + (b >> 3);
    int bm = swz >> 4;            // M/BM = 128
    int bn = swz & 15;            // N/BN = 16

    int tid = threadIdx.x;
    int lane = tid & 63;
    int w = tid >> 6;
    int wm = w >> 2, wn = w & 3;  // 2x4 wave grid, wave tile 64x64

    f32x16 acc[2][2];
#pragma unroll
    for (int i = 0; i < 2; ++i)
#pragma unroll
        for (int j = 0; j < 2; ++j) acc[i][j] = (f32x16)0.f;

    const unsigned char* Aseg = qa + (long)(bm * 4) * NK64 * 2048;
    const unsigned char* Bseg = qw + (long)(bn * 8) * NK64 * 2048;
    unsigned char* sbase = &lds[0][0];

    // prologue: stage tiles 0,1 (depth-2; 6 vmem per thread)
    stage_q(Aseg, Bseg, sbase + 0 * BUFB, tid, 0);
    stage_q(Aseg, Bseg, sbase + 1 * BUFB, tid, 1);

#pragma unroll 1
    for (int kt = 0; kt < 62; ++kt)
        tile_step<3, true>(sbase, Aseg, Bseg, kt, tid, lane, wm, wn, acc);
    tile_step<3, false>(sbase, Aseg, Bseg, 62, tid, lane, wm, wn, acc);
    tile_step<0, false>(sbase, Aseg, Bseg, 63, tid, lane, wm, wn, acc);

    // epilogue: dequant scale = (amax_x/448) * (amax_w/448)
    float ax = fmaxf(__uint_as_float(amax[0]), 1e-12f);
    float aw = fmaxf(__uint_as_float(amax[1]), 1e-12f);
    float s = ax * aw * (1.0f / (FP8_MAX * FP8_MAX));

    long m0 = (long)bm * BM + wm * 64;
    long n0 = (long)bn * BN + wn * 64;
    int col = lane & 31;
    int rbase = 4 * (lane >> 5);
#pragma unroll
    for (int i = 0; i < 2; ++i)
#pragma unroll
        for (int j = 0; j < 2; ++j)
#pragma unroll
            for (int reg = 0; reg < 16; ++reg) {
                int row = (reg & 3) + 8 * (reg >> 2) + rbase;
                out[(m0 + i * 32 + row) * N_DIM + n0 + j * 32 + col] =
                    acc[i][j][reg] * s;
            }
}

extern "C" void kernel_launch(void* const* d_in, const int* in_sizes, int n_in,
                              void* d_out, int out_size, void* d_ws, size_t ws_size,
                              hipStream_t stream) {
    const float* x = (const float*)d_in[0];       // (8,2048,4096) = (M,K)
    const float* wgt = (const float*)d_in[1];     // (K,N)
    float* out = (float*)d_out;

    // workspace layout
    unsigned* amax = (unsigned*)d_ws;                         // 2 words
    unsigned char* qa = (unsigned char*)d_ws + 256;           // M*K fp8 = 64MB packed
    unsigned char* qw = qa + (long)M_DIM * K_DIM;             // N*K fp8 = 16MB packed

    init_amax_kernel<<<1, 64, 0, stream>>>(amax);
    amax2_kernel<<<3072, 256, 0, stream>>>(x, wgt, amax);
    quant_kernel<<<4608, 256, 0, stream>>>(x, wgt, qa, qw, amax);

    dim3 grid((M_DIM / BM) * (N_DIM / BN));  // 2048
    gemm_fp8_kernel<<<grid, 512, 0, stream>>>(qa, qw, out, amax);
}

// Round 15
// 441.765 us; speedup vs baseline: 1.0361x; 1.0361x over previous
//
#include <hip/hip_runtime.h>
#include <hip/hip_bf16.h>

#define M_DIM 16384
#define N_DIM 4096
#define K_DIM 4096
#define FP8_MAX 448.0f

#define BM 256
#define BN 256
#define NK64 (K_DIM / 64)   // 64 k64-blocks = K-tiles

typedef float f32x16 __attribute__((ext_vector_type(16)));
typedef int i32x4 __attribute__((ext_vector_type(4)));
typedef int i32x8 __attribute__((ext_vector_type(8)));

// 8-wide MFMA operand whose halves are filled directly by ds_read_b128 —
// avoids the 8x v_mov shufflevector materialization (VALUBusy cut).
typedef union {
    i32x8 v;
    struct { i32x4 lo, hi; } p;
} frag8;

// Packed fp8 operand layout (A and B identical), matched to the
// mfma_scale_f32_32x32x64_f8f6f4 fragment: lane l holds
//   row = row32*32 + (l&31),  k = k64*64 + (l>>5)*32 + h*16 + j  (h=0,1; j=0..15)
// stored as [row32-block][k64-block][h][lane][16B]  (block = 2048 B).
// GEMM = R13 (passing, 254us): 256x256 tile, reg-double-buffered, 2-phase:
//   gate(vmcnt4+lgkm0) -> bar -> {reads A0,A1,B0 (kt+1); stages r0,r1 (kt+3);
//   MFMA col0} -> mid bar -> {reads A2,A3,B1; stages r2,r3; MFMA col1}.
// Only change this round: frag8 unions replace comb() shufflevector.
// scales = 1.0 e8m0 -> bit-identical to plain fp8 GEMM math.

// ---------------- init ----------------
__global__ void init_amax_kernel(unsigned* amax) {
    if (threadIdx.x < 2) amax[threadIdx.x] = 0u;
}

// ---------------- fused amax reduction (x then w) ----------------
__global__ void amax2_kernel(const float* __restrict__ x,
                             const float* __restrict__ w,
                             unsigned* __restrict__ amax) {
    const float* p;
    long n4;
    unsigned* out;
    long bid, nb;
    if (blockIdx.x < 2048) {
        p = x; n4 = (long)M_DIM * K_DIM / 4; out = amax + 0;
        bid = blockIdx.x; nb = 2048;
    } else {
        p = w; n4 = (long)K_DIM * N_DIM / 4; out = amax + 1;
        bid = blockIdx.x - 2048; nb = 1024;
    }
    float m = 0.f;
    const float4* p4 = (const float4*)p;
    for (long i = bid * blockDim.x + threadIdx.x; i < n4; i += nb * blockDim.x) {
        float4 v = p4[i];
        m = fmaxf(m, fmaxf(fmaxf(fabsf(v.x), fabsf(v.y)),
                           fmaxf(fabsf(v.z), fabsf(v.w))));
    }
#pragma unroll
    for (int off = 32; off > 0; off >>= 1)
        m = fmaxf(m, __shfl_down(m, off));
    __shared__ float smax[4];
    int lane = threadIdx.x & 63, wid = threadIdx.x >> 6;
    if (lane == 0) smax[wid] = m;
    __syncthreads();
    if (threadIdx.x == 0) {
        float bm = fmaxf(fmaxf(smax[0], smax[1]), fmaxf(smax[2], smax[3]));
        atomicMax(out, __float_as_uint(bm));  // positive floats: bit order == value order
    }
}

__device__ __forceinline__ unsigned pack4(float4 v, float s) {
    float a = fminf(fmaxf(v.x * s, -FP8_MAX), FP8_MAX);
    float b = fminf(fmaxf(v.y * s, -FP8_MAX), FP8_MAX);
    float c = fminf(fmaxf(v.z * s, -FP8_MAX), FP8_MAX);
    float d = fminf(fmaxf(v.w * s, -FP8_MAX), FP8_MAX);
    int p = 0;
    p = __builtin_amdgcn_cvt_pk_fp8_f32(a, b, p, false);
    p = __builtin_amdgcn_cvt_pk_fp8_f32(c, d, p, true);
    return (unsigned)p;
}

// -------- fused quantize: blocks 0..511 -> x ; 512..4607 -> weight --------
__global__ void quant_kernel(const float* __restrict__ x,
                             const float* __restrict__ w,
                             unsigned char* __restrict__ qa,
                             unsigned char* __restrict__ qw,
                             const unsigned* __restrict__ amax) {
    __shared__ unsigned tile[64][17];     // used by the weight path only
    int t = threadIdx.x;
    if (blockIdx.x < 512) {
        // ---- x path: (M,K) fp32 -> packed fp8 ----
        float scale = FP8_MAX / fmaxf(__uint_as_float(amax[0]), 1e-12f);
        int m32 = blockIdx.x;             // 0..511 (M/32)
        int lane = t & 63;
        int g = t >> 6;                   // 0..3: k64 sub-block per iteration
        int m = m32 * 32 + (lane & 31);
        int kh = lane >> 5;               // k-half of the 64-wide K block
        const float* rp = x + (long)m * K_DIM;
        unsigned char* ob = qa + (long)m32 * NK64 * 2048;
#pragma unroll
        for (int it = 0; it < 16; ++it) { // 64 k64-blocks, 4 per iter
            int k64 = it * 4 + g;
            int kb = k64 * 64 + kh * 32;
            float4 v0 = *(const float4*)&rp[kb];
            float4 v1 = *(const float4*)&rp[kb + 4];
            float4 v2 = *(const float4*)&rp[kb + 8];
            float4 v3 = *(const float4*)&rp[kb + 12];
            float4 v4 = *(const float4*)&rp[kb + 16];
            float4 v5 = *(const float4*)&rp[kb + 20];
            float4 v6 = *(const float4*)&rp[kb + 24];
            float4 v7 = *(const float4*)&rp[kb + 28];
            uint4 o0, o1;
            o0.x = pack4(v0, scale); o0.y = pack4(v1, scale);
            o0.z = pack4(v2, scale); o0.w = pack4(v3, scale);
            o1.x = pack4(v4, scale); o1.y = pack4(v5, scale);
            o1.z = pack4(v6, scale); o1.w = pack4(v7, scale);
            *(uint4*)&ob[(long)k64 * 2048 + lane * 16] = o0;          // h=0
            *(uint4*)&ob[(long)k64 * 2048 + 1024 + lane * 16] = o1;   // h=1
        }
    } else {
        // ---- weight path: (K,N) -> packed fp8 (N-major) ----
        float scale = FP8_MAX / fmaxf(__uint_as_float(amax[1]), 1e-12f);
        int b = blockIdx.x - 512;         // 4096 = (K/64) * (N/64)
        int bk = b & 63, bn = b >> 6;
        int k0 = bk * 64, n0 = bn * 64;
#pragma unroll
        for (int pass = 0; pass < 4; ++pass) {
            int idx = pass * 256 + t;     // 64 k x 16 words
            int k = idx >> 4, nw = idx & 15;
            float4 v = *(const float4*)&w[(long)(k0 + k) * N_DIM + n0 + nw * 4];
            tile[k][nw] = pack4(v, scale);
        }
        __syncthreads();
        int lane = t & 63, g = t >> 6;
        int n32 = g >> 1, h = g & 1;      // 2 n32-blocks x 2 halves
        int nl = n32 * 32 + (lane & 31);
        int word = nl >> 2, sh = (nl & 3) * 8;
        int kb = (lane >> 5) * 32 + h * 16;
        uint4 o;
        unsigned* ow = (unsigned*)&o;
#pragma unroll
        for (int wd = 0; wd < 4; ++wd) {
            unsigned acc = 0;
#pragma unroll
            for (int j = 0; j < 4; ++j)
                acc |= ((tile[kb + wd * 4 + j][word] >> sh) & 0xffu) << (8 * j);
            ow[wd] = acc;
        }
        long gn32 = (long)(n0 >> 5) + n32;
        *(uint4*)&qw[(gn32 * NK64 + bk) * 2048 + h * 1024 + lane * 16] = o;
    }
}

// ---------------- MX-fp8 GEMM, 2-phase paced, reg-double-buffered ----------------
__device__ __forceinline__ void stage_q(const unsigned char* __restrict__ Aseg,
                                        const unsigned char* __restrict__ Bseg,
                                        unsigned char* stbuf, int tid, int kt, int r) {
    int c = r * 512 + tid;                // 0..2047: 1024 A chunks then 1024 B
    int f = (c >> 7) & 7;                 // row32-block 0..7
    int q = c & 127;
    const unsigned char* src =
        ((c < 1024) ? Aseg : Bseg) + ((long)f * NK64 + kt) * 2048 + q * 16;
    __builtin_amdgcn_global_load_lds(
        (const __attribute__((address_space(1))) void*)src,
        (__attribute__((address_space(3))) void*)(stbuf + c * 16), 16, 0, 0);
}

#define SB() __builtin_amdgcn_sched_barrier(0)

// One K-tile step. On entry: frags for tile kt live in (ca, cb).
// Identical sync structure to passing R13; operands now frag8 (no movs).
template <int VW, bool STG, bool NEXT>
__device__ __forceinline__ void tile_step(
    unsigned char* sbase, const unsigned char* __restrict__ Aseg,
    const unsigned char* __restrict__ Bseg, int kt, int tid, int lane,
    int wm, int wn, frag8 (&ca)[4], frag8 (&cb)[2],
    frag8 (&na)[4], frag8 (&nb)[2], f32x16 (&acc)[4][2]) {
    // gate: own staging loads for tile kt+1 landed AND own ds_reads drained;
    // then barrier -> ALL waves' staging for tile kt+1 visible (cross-wave).
    if constexpr (VW == 4)
        asm volatile("s_waitcnt vmcnt(4) lgkmcnt(0)" ::: "memory");
    else if constexpr (VW == 0)
        asm volatile("s_waitcnt vmcnt(0) lgkmcnt(0)" ::: "memory");
    if constexpr (VW >= 0) {
        SB();
        __builtin_amdgcn_s_barrier();
        SB();
    }

    const unsigned char* nbuf = sbase + (size_t)((kt + 1) & 3) * 32768;
    const unsigned char* nAl = nbuf + wm * 4 * 2048 + lane * 16;
    const unsigned char* nBl = nbuf + 16384 + wn * 2 * 2048 + lane * 16;
    unsigned char* stbuf = sbase + (size_t)((kt + 3) & 3) * 32768;

    // ---- phase 0: reads A0,A1,B0 of kt+1 ; stages r0,r1 ; MFMA col 0 ----
    if constexpr (NEXT) {
        na[0].p.lo = *(const i32x4*)(nAl + 0 * 2048);
        na[0].p.hi = *(const i32x4*)(nAl + 0 * 2048 + 1024);
        na[1].p.lo = *(const i32x4*)(nAl + 1 * 2048);
        na[1].p.hi = *(const i32x4*)(nAl + 1 * 2048 + 1024);
        nb[0].p.lo = *(const i32x4*)(nBl);
        nb[0].p.hi = *(const i32x4*)(nBl + 1024);
    }
    if constexpr (STG) {
        stage_q(Aseg, Bseg, stbuf, tid, kt + 3, 0);
        stage_q(Aseg, Bseg, stbuf, tid, kt + 3, 1);
    }
    SB();
    __builtin_amdgcn_s_setprio(1);
#pragma unroll
    for (int i = 0; i < 4; ++i)
        acc[i][0] = __builtin_amdgcn_mfma_scale_f32_32x32x64_f8f6f4(
            ca[i].v, cb[0].v, acc[i][0],
            0, 0, 0, 0x7f7f7f7f, 0, 0x7f7f7f7f);
    __builtin_amdgcn_s_setprio(0);
    SB();
    __builtin_amdgcn_s_barrier();     // mid pacing barrier (uniform, data-free)
    SB();

    // ---- phase 1: reads A2,A3,B1 of kt+1 ; stages r2,r3 ; MFMA col 1 ----
    if constexpr (NEXT) {
        na[2].p.lo = *(const i32x4*)(nAl + 2 * 2048);
        na[2].p.hi = *(const i32x4*)(nAl + 2 * 2048 + 1024);
        na[3].p.lo = *(const i32x4*)(nAl + 3 * 2048);
        na[3].p.hi = *(const i32x4*)(nAl + 3 * 2048 + 1024);
        nb[1].p.lo = *(const i32x4*)(nBl + 2048);
        nb[1].p.hi = *(const i32x4*)(nBl + 2048 + 1024);
    }
    if constexpr (STG) {
        stage_q(Aseg, Bseg, stbuf, tid, kt + 3, 2);
        stage_q(Aseg, Bseg, stbuf, tid, kt + 3, 3);
    }
    SB();
    __builtin_amdgcn_s_setprio(1);
#pragma unroll
    for (int i = 0; i < 4; ++i)
        acc[i][1] = __builtin_amdgcn_mfma_scale_f32_32x32x64_f8f6f4(
            ca[i].v, cb[1].v, acc[i][1],
            0, 0, 0, 0x7f7f7f7f, 0, 0x7f7f7f7f);
    __builtin_amdgcn_s_setprio(0);
}

__global__ __launch_bounds__(512, 2) void gemm_fp8_kernel(
    const unsigned char* __restrict__ qa, const unsigned char* __restrict__ qw,
    float* __restrict__ out, const unsigned* __restrict__ amax) {
    __shared__ unsigned char lds[4][32768];   // 128 KB: 4 buffers (A 16K + B 16K)

    // XCD-bijective swizzle (nwg = 1024, divisible by 8)
    int b = blockIdx.x;
    int swz = (b & 7) * 128 + (b >> 3);
    int bm = swz >> 4;            // M/BM = 64 ; N/BN = 16
    int bn = swz & 15;

    int tid = threadIdx.x;
    int lane = tid & 63;
    int w = tid >> 6;
    int wm = w >> 2, wn = w & 3;  // 2x4 wave grid, wave tile 128x64

    f32x16 acc[4][2];
#pragma unroll
    for (int i = 0; i < 4; ++i)
#pragma unroll
        for (int j = 0; j < 2; ++j) acc[i][j] = (f32x16)0.f;

    const unsigned char* Aseg = qa + (long)(bm * 8) * NK64 * 2048;
    const unsigned char* Bseg = qw + (long)(bn * 8) * NK64 * 2048;
    unsigned char* sbase = &lds[0][0];

    frag8 A0[4], B0[2], A1[4], B1[2];

    // prologue: stage tiles 0,1,2 (depth-3)
#pragma unroll
    for (int pt = 0; pt < 3; ++pt)
#pragma unroll
        for (int r = 0; r < 4; ++r)
            stage_q(Aseg, Bseg, sbase + (size_t)pt * 32768, tid, pt, r);
    asm volatile("s_waitcnt vmcnt(0)" ::: "memory");   // all staged tiles resident
    SB();
    __builtin_amdgcn_s_barrier();                      // ..for all waves
    SB();
    {   // read tile-0 fragments
        const unsigned char* Al = sbase + wm * 4 * 2048 + lane * 16;
        const unsigned char* Bl = sbase + 16384 + wn * 2 * 2048 + lane * 16;
#pragma unroll
        for (int i = 0; i < 4; ++i) {
            A0[i].p.lo = *(const i32x4*)(Al + i * 2048);
            A0[i].p.hi = *(const i32x4*)(Al + i * 2048 + 1024);
        }
#pragma unroll
        for (int j = 0; j < 2; ++j) {
            B0[j].p.lo = *(const i32x4*)(Bl + j * 2048);
            B0[j].p.hi = *(const i32x4*)(Bl + j * 2048 + 1024);
        }
    }

    // step 0 (no gate): uses (A0,B0); reads tile-1 frags; stages tile 3
    tile_step<-1, true, true>(sbase, Aseg, Bseg, 0, tid, lane, wm, wn,
                              A0, B0, A1, B1, acc);
#pragma unroll 1
    for (int kt = 1; kt < 61; kt += 2) {   // covers kt = 1..60
        tile_step<4, true, true>(sbase, Aseg, Bseg, kt, tid, lane, wm, wn,
                                 A1, B1, A0, B0, acc);
        tile_step<4, true, true>(sbase, Aseg, Bseg, kt + 1, tid, lane, wm, wn,
                                 A0, B0, A1, B1, acc);
    }
    tile_step<4, false, true>(sbase, Aseg, Bseg, 61, tid, lane, wm, wn,
                              A1, B1, A0, B0, acc);
    tile_step<0, false, true>(sbase, Aseg, Bseg, 62, tid, lane, wm, wn,
                              A0, B0, A1, B1, acc);
    tile_step<-1, false, false>(sbase, Aseg, Bseg, 63, tid, lane, wm, wn,
                                A1, B1, A0, B0, acc);

    // epilogue: dequant scale = (amax_x/448) * (amax_w/448)
    float ax = fmaxf(__uint_as_float(amax[0]), 1e-12f);
    float aw = fmaxf(__uint_as_float(amax[1]), 1e-12f);
    float s = ax * aw * (1.0f / (FP8_MAX * FP8_MAX));

    long m0 = (long)bm * BM + wm * 128;
    long n0 = (long)bn * BN + wn * 64;
    int col = lane & 31;
    int rbase = 4 * (lane >> 5);
#pragma unroll
    for (int i = 0; i < 4; ++i)
#pragma unroll
        for (int j = 0; j < 2; ++j)
#pragma unroll
            for (int reg = 0; reg < 16; ++reg) {
                int row = (reg & 3) + 8 * (reg >> 2) + rbase;
                out[(m0 + i * 32 + row) * N_DIM + n0 + j * 32 + col] =
                    acc[i][j][reg] * s;
            }
}

extern "C" void kernel_launch(void* const* d_in, const int* in_sizes, int n_in,
                              void* d_out, int out_size, void* d_ws, size_t ws_size,
                              hipStream_t stream) {
    const float* x = (const float*)d_in[0];       // (8,2048,4096) = (M,K)
    const float* wgt = (const float*)d_in[1];     // (K,N)
    float* out = (float*)d_out;

    // workspace layout
    unsigned* amax = (unsigned*)d_ws;                         // 2 words
    unsigned char* qa = (unsigned char*)d_ws + 256;           // M*K fp8 = 64MB packed
    unsigned char* qw = qa + (long)M_DIM * K_DIM;             // N*K fp8 = 16MB packed

    init_amax_kernel<<<1, 64, 0, stream>>>(amax);
    amax2_kernel<<<3072, 256, 0, stream>>>(x, wgt, amax);
    quant_kernel<<<4608, 256, 0, stream>>>(x, wgt, qa, qw, amax);

    dim3 grid((M_DIM / BM) * (N_DIM / BN));  // 1024
    gemm_fp8_kernel<<<grid, 512, 0, stream>>>(qa, qw, out, amax);
}

// Round 16
// 428.775 us; speedup vs baseline: 1.0675x; 1.0303x over previous
//
#include <hip/hip_runtime.h>
#include <hip/hip_bf16.h>

#define M_DIM 16384
#define N_DIM 4096
#define K_DIM 4096
#define FP8_MAX 448.0f

#define BM 256
#define BN 256
#define NK64 (K_DIM / 64)   // 64 k64-blocks = K-tiles

typedef float f32x16 __attribute__((ext_vector_type(16)));
typedef int i32x4 __attribute__((ext_vector_type(4)));
typedef int i32x8 __attribute__((ext_vector_type(8)));

// 8-wide MFMA operand whose halves are filled directly by ds_read_b128.
typedef union {
    i32x8 v;
    struct { i32x4 lo, hi; } p;
} frag8;

// Packed fp8 operand layout (A and B identical), matched to the
// mfma_scale_f32_32x32x64_f8f6f4 fragment: lane l holds
//   row = row32*32 + (l&31),  k = k64*64 + (l>>5)*32 + h*16 + j  (h=0,1; j=0..15)
// stored as [row32-block][k64-block][h][lane][16B]  (block = 2048 B).
// GEMM = R15 (passing, ~255us) VERBATIM. This round: quant_x rewritten with
// coalesced reads + LDS transpose (old path read at 16KB/lane stride).
// scales = 1.0 e8m0 -> bit-identical to plain fp8 GEMM math.

// ---------------- init ----------------
__global__ void init_amax_kernel(unsigned* amax) {
    if (threadIdx.x < 2) amax[threadIdx.x] = 0u;
}

// ---------------- fused amax reduction (x then w) ----------------
__global__ void amax2_kernel(const float* __restrict__ x,
                             const float* __restrict__ w,
                             unsigned* __restrict__ amax) {
    const float* p;
    long n4;
    unsigned* out;
    long bid, nb;
    if (blockIdx.x < 2048) {
        p = x; n4 = (long)M_DIM * K_DIM / 4; out = amax + 0;
        bid = blockIdx.x; nb = 2048;
    } else {
        p = w; n4 = (long)K_DIM * N_DIM / 4; out = amax + 1;
        bid = blockIdx.x - 2048; nb = 1024;
    }
    float m = 0.f;
    const float4* p4 = (const float4*)p;
    for (long i = bid * blockDim.x + threadIdx.x; i < n4; i += nb * blockDim.x) {
        float4 v = p4[i];
        m = fmaxf(m, fmaxf(fmaxf(fabsf(v.x), fabsf(v.y)),
                           fmaxf(fabsf(v.z), fabsf(v.w))));
    }
#pragma unroll
    for (int off = 32; off > 0; off >>= 1)
        m = fmaxf(m, __shfl_down(m, off));
    __shared__ float smax[4];
    int lane = threadIdx.x & 63, wid = threadIdx.x >> 6;
    if (lane == 0) smax[wid] = m;
    __syncthreads();
    if (threadIdx.x == 0) {
        float bm = fmaxf(fmaxf(smax[0], smax[1]), fmaxf(smax[2], smax[3]));
        atomicMax(out, __float_as_uint(bm));  // positive floats: bit order == value order
    }
}

__device__ __forceinline__ unsigned pack4(float4 v, float s) {
    float a = fminf(fmaxf(v.x * s, -FP8_MAX), FP8_MAX);
    float b = fminf(fmaxf(v.y * s, -FP8_MAX), FP8_MAX);
    float c = fminf(fmaxf(v.z * s, -FP8_MAX), FP8_MAX);
    float d = fminf(fmaxf(v.w * s, -FP8_MAX), FP8_MAX);
    int p = 0;
    p = __builtin_amdgcn_cvt_pk_fp8_f32(a, b, p, false);
    p = __builtin_amdgcn_cvt_pk_fp8_f32(c, d, p, true);
    return (unsigned)p;
}

// -------- fused quantize: blocks 0..2047 -> x ; 2048..6143 -> weight --------
// x path: block = (m32, kq); handles 32 rows x 16 k64-blocks via LDS bounce.
//   read: t -> row t>>3, k-words (t&7)*2 (coalesced 256B per 8 lanes)
//   emit: t -> byte offset t*8 of the 2048B packed block (fully coalesced)
__global__ void quant_kernel(const float* __restrict__ x,
                             const float* __restrict__ w,
                             unsigned char* __restrict__ qa,
                             unsigned char* __restrict__ qw,
                             const unsigned* __restrict__ amax) {
    __shared__ unsigned tile[64][17];     // x path uses [32][17]; wt uses [64][17]
    int t = threadIdx.x;
    if (blockIdx.x < 2048) {
        // ---- x path: (M,K) fp32 -> packed fp8, coalesced via LDS ----
        float scale = FP8_MAX / fmaxf(__uint_as_float(amax[0]), 1e-12f);
        int m32 = blockIdx.x >> 2;        // 0..511
        int kq = blockIdx.x & 3;          // k-quarter: k64 in [kq*16, kq*16+16)
        int rin = t >> 3;                 // input row 0..31
        int win = (t & 7) * 2;            // input k-word pair
        const float* rp = x + (long)(m32 * 32 + rin) * K_DIM;
        unsigned char* ob = qa + (long)m32 * NK64 * 2048;
        // output decomposition: byte offset t*8 within the 2048B block
        int h = t >> 7;                   // 0..1
        int lo = (t & 127) >> 1;          // lane 0..63
        int half = t & 1;                 // 8B half of the lane's 16B
        int rowо = lo & 31;
        int kw0 = (lo >> 5) * 8 + h * 4 + half * 2;
#pragma unroll
        for (int it = 0; it < 16; ++it) {
            int k64 = kq * 16 + it;
            float4 v0 = *(const float4*)&rp[k64 * 64 + win * 4];
            float4 v1 = *(const float4*)&rp[k64 * 64 + win * 4 + 4];
            unsigned u0 = pack4(v0, scale);
            unsigned u1 = pack4(v1, scale);
            __syncthreads();              // tile free from previous iter
            tile[rin][win] = u0;
            tile[rin][win + 1] = u1;
            __syncthreads();
            uint2 o;
            o.x = tile[rowо][kw0];
            o.y = tile[rowо][kw0 + 1];
            *(uint2*)&ob[(long)k64 * 2048 + t * 8] = o;
        }
    } else {
        // ---- weight path: (K,N) -> packed fp8 (N-major) ----
        float scale = FP8_MAX / fmaxf(__uint_as_float(amax[1]), 1e-12f);
        int b = blockIdx.x - 2048;        // 4096 = (K/64) * (N/64)
        int bk = b & 63, bn = b >> 6;
        int k0 = bk * 64, n0 = bn * 64;
#pragma unroll
        for (int pass = 0; pass < 4; ++pass) {
            int idx = pass * 256 + t;     // 64 k x 16 words
            int k = idx >> 4, nw = idx & 15;
            float4 v = *(const float4*)&w[(long)(k0 + k) * N_DIM + n0 + nw * 4];
            tile[k][nw] = pack4(v, scale);
        }
        __syncthreads();
        int lane = t & 63, g = t >> 6;
        int n32 = g >> 1, h = g & 1;      // 2 n32-blocks x 2 halves
        int nl = n32 * 32 + (lane & 31);
        int word = nl >> 2, sh = (nl & 3) * 8;
        int kb = (lane >> 5) * 32 + h * 16;
        uint4 o;
        unsigned* ow = (unsigned*)&o;
#pragma unroll
        for (int wd = 0; wd < 4; ++wd) {
            unsigned acc = 0;
#pragma unroll
            for (int j = 0; j < 4; ++j)
                acc |= ((tile[kb + wd * 4 + j][word] >> sh) & 0xffu) << (8 * j);
            ow[wd] = acc;
        }
        long gn32 = (long)(n0 >> 5) + n32;
        *(uint4*)&qw[(gn32 * NK64 + bk) * 2048 + h * 1024 + lane * 16] = o;
    }
}

// ---------------- MX-fp8 GEMM, 2-phase paced, reg-double-buffered ----------------
__device__ __forceinline__ void stage_q(const unsigned char* __restrict__ Aseg,
                                        const unsigned char* __restrict__ Bseg,
                                        unsigned char* stbuf, int tid, int kt, int r) {
    int c = r * 512 + tid;                // 0..2047: 1024 A chunks then 1024 B
    int f = (c >> 7) & 7;                 // row32-block 0..7
    int q = c & 127;
    const unsigned char* src =
        ((c < 1024) ? Aseg : Bseg) + ((long)f * NK64 + kt) * 2048 + q * 16;
    __builtin_amdgcn_global_load_lds(
        (const __attribute__((address_space(1))) void*)src,
        (__attribute__((address_space(3))) void*)(stbuf + c * 16), 16, 0, 0);
}

#define SB() __builtin_amdgcn_sched_barrier(0)

// One K-tile step. On entry: frags for tile kt live in (ca, cb).
template <int VW, bool STG, bool NEXT>
__device__ __forceinline__ void tile_step(
    unsigned char* sbase, const unsigned char* __restrict__ Aseg,
    const unsigned char* __restrict__ Bseg, int kt, int tid, int lane,
    int wm, int wn, frag8 (&ca)[4], frag8 (&cb)[2],
    frag8 (&na)[4], frag8 (&nb)[2], f32x16 (&acc)[4][2]) {
    // gate: own staging loads for tile kt+1 landed AND own ds_reads drained;
    // then barrier -> ALL waves' staging for tile kt+1 visible (cross-wave).
    if constexpr (VW == 4)
        asm volatile("s_waitcnt vmcnt(4) lgkmcnt(0)" ::: "memory");
    else if constexpr (VW == 0)
        asm volatile("s_waitcnt vmcnt(0) lgkmcnt(0)" ::: "memory");
    if constexpr (VW >= 0) {
        SB();
        __builtin_amdgcn_s_barrier();
        SB();
    }

    const unsigned char* nbuf = sbase + (size_t)((kt + 1) & 3) * 32768;
    const unsigned char* nAl = nbuf + wm * 4 * 2048 + lane * 16;
    const unsigned char* nBl = nbuf + 16384 + wn * 2 * 2048 + lane * 16;
    unsigned char* stbuf = sbase + (size_t)((kt + 3) & 3) * 32768;

    // ---- phase 0: reads A0,A1,B0 of kt+1 ; stages r0,r1 ; MFMA col 0 ----
    if constexpr (NEXT) {
        na[0].p.lo = *(const i32x4*)(nAl + 0 * 2048);
        na[0].p.hi = *(const i32x4*)(nAl + 0 * 2048 + 1024);
        na[1].p.lo = *(const i32x4*)(nAl + 1 * 2048);
        na[1].p.hi = *(const i32x4*)(nAl + 1 * 2048 + 1024);
        nb[0].p.lo = *(const i32x4*)(nBl);
        nb[0].p.hi = *(const i32x4*)(nBl + 1024);
    }
    if constexpr (STG) {
        stage_q(Aseg, Bseg, stbuf, tid, kt + 3, 0);
        stage_q(Aseg, Bseg, stbuf, tid, kt + 3, 1);
    }
    SB();
    __builtin_amdgcn_s_setprio(1);
#pragma unroll
    for (int i = 0; i < 4; ++i)
        acc[i][0] = __builtin_amdgcn_mfma_scale_f32_32x32x64_f8f6f4(
            ca[i].v, cb[0].v, acc[i][0],
            0, 0, 0, 0x7f7f7f7f, 0, 0x7f7f7f7f);
    __builtin_amdgcn_s_setprio(0);
    SB();
    __builtin_amdgcn_s_barrier();     // mid pacing barrier (uniform, data-free)
    SB();

    // ---- phase 1: reads A2,A3,B1 of kt+1 ; stages r2,r3 ; MFMA col 1 ----
    if constexpr (NEXT) {
        na[2].p.lo = *(const i32x4*)(nAl + 2 * 2048);
        na[2].p.hi = *(const i32x4*)(nAl + 2 * 2048 + 1024);
        na[3].p.lo = *(const i32x4*)(nAl + 3 * 2048);
        na[3].p.hi = *(const i32x4*)(nAl + 3 * 2048 + 1024);
        nb[1].p.lo = *(const i32x4*)(nBl + 2048);
        nb[1].p.hi = *(const i32x4*)(nBl + 2048 + 1024);
    }
    if constexpr (STG) {
        stage_q(Aseg, Bseg, stbuf, tid, kt + 3, 2);
        stage_q(Aseg, Bseg, stbuf, tid, kt + 3, 3);
    }
    SB();
    __builtin_amdgcn_s_setprio(1);
#pragma unroll
    for (int i = 0; i < 4; ++i)
        acc[i][1] = __builtin_amdgcn_mfma_scale_f32_32x32x64_f8f6f4(
            ca[i].v, cb[1].v, acc[i][1],
            0, 0, 0, 0x7f7f7f7f, 0, 0x7f7f7f7f);
    __builtin_amdgcn_s_setprio(0);
}

__global__ __launch_bounds__(512, 2) void gemm_fp8_kernel(
    const unsigned char* __restrict__ qa, const unsigned char* __restrict__ qw,
    float* __restrict__ out, const unsigned* __restrict__ amax) {
    __shared__ unsigned char lds[4][32768];   // 128 KB: 4 buffers (A 16K + B 16K)

    // XCD-bijective swizzle (nwg = 1024, divisible by 8)
    int b = blockIdx.x;
    int swz = (b & 7) * 128 + (b >> 3);
    int bm = swz >> 4;            // M/BM = 64 ; N/BN = 16
    int bn = swz & 15;

    int tid = threadIdx.x;
    int lane = tid & 63;
    int w = tid >> 6;
    int wm = w >> 2, wn = w & 3;  // 2x4 wave grid, wave tile 128x64

    f32x16 acc[4][2];
#pragma unroll
    for (int i = 0; i < 4; ++i)
#pragma unroll
        for (int j = 0; j < 2; ++j) acc[i][j] = (f32x16)0.f;

    const unsigned char* Aseg = qa + (long)(bm * 8) * NK64 * 2048;
    const unsigned char* Bseg = qw + (long)(bn * 8) * NK64 * 2048;
    unsigned char* sbase = &lds[0][0];

    frag8 A0[4], B0[2], A1[4], B1[2];

    // prologue: stage tiles 0,1,2 (depth-3)
#pragma unroll
    for (int pt = 0; pt < 3; ++pt)
#pragma unroll
        for (int r = 0; r < 4; ++r)
            stage_q(Aseg, Bseg, sbase + (size_t)pt * 32768, tid, pt, r);
    asm volatile("s_waitcnt vmcnt(0)" ::: "memory");   // all staged tiles resident
    SB();
    __builtin_amdgcn_s_barrier();                      // ..for all waves
    SB();
    {   // read tile-0 fragments
        const unsigned char* Al = sbase + wm * 4 * 2048 + lane * 16;
        const unsigned char* Bl = sbase + 16384 + wn * 2 * 2048 + lane * 16;
#pragma unroll
        for (int i = 0; i < 4; ++i) {
            A0[i].p.lo = *(const i32x4*)(Al + i * 2048);
            A0[i].p.hi = *(const i32x4*)(Al + i * 2048 + 1024);
        }
#pragma unroll
        for (int j = 0; j < 2; ++j) {
            B0[j].p.lo = *(const i32x4*)(Bl + j * 2048);
            B0[j].p.hi = *(const i32x4*)(Bl + j * 2048 + 1024);
        }
    }

    // step 0 (no gate): uses (A0,B0); reads tile-1 frags; stages tile 3
    tile_step<-1, true, true>(sbase, Aseg, Bseg, 0, tid, lane, wm, wn,
                              A0, B0, A1, B1, acc);
#pragma unroll 1
    for (int kt = 1; kt < 61; kt += 2) {   // covers kt = 1..60
        tile_step<4, true, true>(sbase, Aseg, Bseg, kt, tid, lane, wm, wn,
                                 A1, B1, A0, B0, acc);
        tile_step<4, true, true>(sbase, Aseg, Bseg, kt + 1, tid, lane, wm, wn,
                                 A0, B0, A1, B1, acc);
    }
    tile_step<4, false, true>(sbase, Aseg, Bseg, 61, tid, lane, wm, wn,
                              A1, B1, A0, B0, acc);
    tile_step<0, false, true>(sbase, Aseg, Bseg, 62, tid, lane, wm, wn,
                              A0, B0, A1, B1, acc);
    tile_step<-1, false, false>(sbase, Aseg, Bseg, 63, tid, lane, wm, wn,
                                A1, B1, A0, B0, acc);

    // epilogue: dequant scale = (amax_x/448) * (amax_w/448)
    float ax = fmaxf(__uint_as_float(amax[0]), 1e-12f);
    float aw = fmaxf(__uint_as_float(amax[1]), 1e-12f);
    float s = ax * aw * (1.0f / (FP8_MAX * FP8_MAX));

    long m0 = (long)bm * BM + wm * 128;
    long n0 = (long)bn * BN + wn * 64;
    int col = lane & 31;
    int rbase = 4 * (lane >> 5);
#pragma unroll
    for (int i = 0; i < 4; ++i)
#pragma unroll
        for (int j = 0; j < 2; ++j)
#pragma unroll
            for (int reg = 0; reg < 16; ++reg) {
                int row = (reg & 3) + 8 * (reg >> 2) + rbase;
                out[(m0 + i * 32 + row) * N_DIM + n0 + j * 32 + col] =
                    acc[i][j][reg] * s;
            }
}

extern "C" void kernel_launch(void* const* d_in, const int* in_sizes, int n_in,
                              void* d_out, int out_size, void* d_ws, size_t ws_size,
                              hipStream_t stream) {
    const float* x = (const float*)d_in[0];       // (8,2048,4096) = (M,K)
    const float* wgt = (const float*)d_in[1];     // (K,N)
    float* out = (float*)d_out;

    // workspace layout
    unsigned* amax = (unsigned*)d_ws;                         // 2 words
    unsigned char* qa = (unsigned char*)d_ws + 256;           // M*K fp8 = 64MB packed
    unsigned char* qw = qa + (long)M_DIM * K_DIM;             // N*K fp8 = 16MB packed

    init_amax_kernel<<<1, 64, 0, stream>>>(amax);
    amax2_kernel<<<3072, 256, 0, stream>>>(x, wgt, amax);
    quant_kernel<<<6144, 256, 0, stream>>>(x, wgt, qa, qw, amax);

    dim3 grid((M_DIM / BM) * (N_DIM / BN));  // 1024
    gemm_fp8_kernel<<<grid, 512, 0, stream>>>(qa, qw, out, amax);
}

// Round 17
// 425.288 us; speedup vs baseline: 1.0763x; 1.0082x over previous
//
#include <hip/hip_runtime.h>
#include <hip/hip_bf16.h>

#define M_DIM 16384
#define N_DIM 4096
#define K_DIM 4096
#define FP8_MAX 448.0f

#define BM 256
#define BN 256
#define NK64 (K_DIM / 64)   // 64 k64-blocks = K-tiles

typedef float f32x16 __attribute__((ext_vector_type(16)));
typedef int i32x4 __attribute__((ext_vector_type(4)));
typedef int i32x8 __attribute__((ext_vector_type(8)));

// 8-wide MFMA operand whose halves are filled directly by ds_read_b128.
typedef union {
    i32x8 v;
    struct { i32x4 lo, hi; } p;
} frag8;

// Packed fp8 operand layout (A and B identical), matched to the
// mfma_scale_f32_32x32x64_f8f6f4 fragment: lane l holds
//   row = row32*32 + (l&31),  k = k64*64 + (l>>5)*32 + h*16 + j  (h=0,1; j=0..15)
// stored as [row32-block][k64-block][h][lane][16B]  (block = 2048 B).
// GEMM = R16 (passing, ~250us) VERBATIM. This round: init kernel replaced by
// hipMemsetAsync; quant_x LDS bounce double-buffered (1 sync/iter not 2).
// scales = 1.0 e8m0 -> bit-identical to plain fp8 GEMM math.

// ---------------- fused amax reduction (x then w) ----------------
__global__ void amax2_kernel(const float* __restrict__ x,
                             const float* __restrict__ w,
                             unsigned* __restrict__ amax) {
    const float* p;
    long n4;
    unsigned* out;
    long bid, nb;
    if (blockIdx.x < 2048) {
        p = x; n4 = (long)M_DIM * K_DIM / 4; out = amax + 0;
        bid = blockIdx.x; nb = 2048;
    } else {
        p = w; n4 = (long)K_DIM * N_DIM / 4; out = amax + 1;
        bid = blockIdx.x - 2048; nb = 1024;
    }
    float m = 0.f;
    const float4* p4 = (const float4*)p;
    for (long i = bid * blockDim.x + threadIdx.x; i < n4; i += nb * blockDim.x) {
        float4 v = p4[i];
        m = fmaxf(m, fmaxf(fmaxf(fabsf(v.x), fabsf(v.y)),
                           fmaxf(fabsf(v.z), fabsf(v.w))));
    }
#pragma unroll
    for (int off = 32; off > 0; off >>= 1)
        m = fmaxf(m, __shfl_down(m, off));
    __shared__ float smax[4];
    int lane = threadIdx.x & 63, wid = threadIdx.x >> 6;
    if (lane == 0) smax[wid] = m;
    __syncthreads();
    if (threadIdx.x == 0) {
        float bm = fmaxf(fmaxf(smax[0], smax[1]), fmaxf(smax[2], smax[3]));
        atomicMax(out, __float_as_uint(bm));  // positive floats: bit order == value order
    }
}

__device__ __forceinline__ unsigned pack4(float4 v, float s) {
    float a = fminf(fmaxf(v.x * s, -FP8_MAX), FP8_MAX);
    float b = fminf(fmaxf(v.y * s, -FP8_MAX), FP8_MAX);
    float c = fminf(fmaxf(v.z * s, -FP8_MAX), FP8_MAX);
    float d = fminf(fmaxf(v.w * s, -FP8_MAX), FP8_MAX);
    int p = 0;
    p = __builtin_amdgcn_cvt_pk_fp8_f32(a, b, p, false);
    p = __builtin_amdgcn_cvt_pk_fp8_f32(c, d, p, true);
    return (unsigned)p;
}

// -------- fused quantize: blocks 0..2047 -> x ; 2048..6143 -> weight --------
// x path: block = (m32, kq); 32 rows x 16 k64-blocks via double-buffered LDS:
//   read: t -> row t>>3, k-words (t&7)*2 (coalesced)
//   emit: t -> byte offset t*8 of the 2048B packed block (fully coalesced)
//   write(cur) -> sync -> read(cur); iter it+1 writes buf (it+1)&1, ordered
//   after all reads@it-1 by the sync inside iter it -> 1 sync/iter is safe.
__global__ void quant_kernel(const float* __restrict__ x,
                             const float* __restrict__ w,
                             unsigned char* __restrict__ qa,
                             unsigned char* __restrict__ qw,
                             const unsigned* __restrict__ amax) {
    __shared__ unsigned tile[2][32][17];  // x: 2 bounce buffers; wt: cast to [64][17]
    int t = threadIdx.x;
    if (blockIdx.x < 2048) {
        // ---- x path: (M,K) fp32 -> packed fp8, coalesced via LDS ----
        float scale = FP8_MAX / fmaxf(__uint_as_float(amax[0]), 1e-12f);
        int m32 = blockIdx.x >> 2;        // 0..511
        int kq = blockIdx.x & 3;          // k-quarter: k64 in [kq*16, kq*16+16)
        int rin = t >> 3;                 // input row 0..31
        int win = (t & 7) * 2;            // input k-word pair
        const float* rp = x + (long)(m32 * 32 + rin) * K_DIM;
        unsigned char* ob = qa + (long)m32 * NK64 * 2048;
        // output decomposition: byte offset t*8 within the 2048B block
        int h = t >> 7;                   // 0..1
        int lo = (t & 127) >> 1;          // lane 0..63
        int half = t & 1;                 // 8B half of the lane's 16B
        int rowo = lo & 31;
        int kw0 = (lo >> 5) * 8 + h * 4 + half * 2;
#pragma unroll
        for (int it = 0; it < 16; ++it) {
            int k64 = kq * 16 + it;
            int cur = it & 1;
            float4 v0 = *(const float4*)&rp[k64 * 64 + win * 4];
            float4 v1 = *(const float4*)&rp[k64 * 64 + win * 4 + 4];
            tile[cur][rin][win] = pack4(v0, scale);
            tile[cur][rin][win + 1] = pack4(v1, scale);
            __syncthreads();
            uint2 o;
            o.x = tile[cur][rowo][kw0];
            o.y = tile[cur][rowo][kw0 + 1];
            *(uint2*)&ob[(long)k64 * 2048 + t * 8] = o;
        }
    } else {
        // ---- weight path: (K,N) -> packed fp8 (N-major) ----
        unsigned (*wt)[17] = (unsigned(*)[17])tile;   // [64][17] view
        float scale = FP8_MAX / fmaxf(__uint_as_float(amax[1]), 1e-12f);
        int b = blockIdx.x - 2048;        // 4096 = (K/64) * (N/64)
        int bk = b & 63, bn = b >> 6;
        int k0 = bk * 64, n0 = bn * 64;
#pragma unroll
        for (int pass = 0; pass < 4; ++pass) {
            int idx = pass * 256 + t;     // 64 k x 16 words
            int k = idx >> 4, nw = idx & 15;
            float4 v = *(const float4*)&w[(long)(k0 + k) * N_DIM + n0 + nw * 4];
            wt[k][nw] = pack4(v, scale);
        }
        __syncthreads();
        int lane = t & 63, g = t >> 6;
        int n32 = g >> 1, h = g & 1;      // 2 n32-blocks x 2 halves
        int nl = n32 * 32 + (lane & 31);
        int word = nl >> 2, sh = (nl & 3) * 8;
        int kb = (lane >> 5) * 32 + h * 16;
        uint4 o;
        unsigned* ow = (unsigned*)&o;
#pragma unroll
        for (int wd = 0; wd < 4; ++wd) {
            unsigned acc = 0;
#pragma unroll
            for (int j = 0; j < 4; ++j)
                acc |= ((wt[kb + wd * 4 + j][word] >> sh) & 0xffu) << (8 * j);
            ow[wd] = acc;
        }
        long gn32 = (long)(n0 >> 5) + n32;
        *(uint4*)&qw[(gn32 * NK64 + bk) * 2048 + h * 1024 + lane * 16] = o;
    }
}

// ---------------- MX-fp8 GEMM, 2-phase paced, reg-double-buffered ----------------
__device__ __forceinline__ void stage_q(const unsigned char* __restrict__ Aseg,
                                        const unsigned char* __restrict__ Bseg,
                                        unsigned char* stbuf, int tid, int kt, int r) {
    int c = r * 512 + tid;                // 0..2047: 1024 A chunks then 1024 B
    int f = (c >> 7) & 7;                 // row32-block 0..7
    int q = c & 127;
    const unsigned char* src =
        ((c < 1024) ? Aseg : Bseg) + ((long)f * NK64 + kt) * 2048 + q * 16;
    __builtin_amdgcn_global_load_lds(
        (const __attribute__((address_space(1))) void*)src,
        (__attribute__((address_space(3))) void*)(stbuf + c * 16), 16, 0, 0);
}

#define SB() __builtin_amdgcn_sched_barrier(0)

// One K-tile step. On entry: frags for tile kt live in (ca, cb).
template <int VW, bool STG, bool NEXT>
__device__ __forceinline__ void tile_step(
    unsigned char* sbase, const unsigned char* __restrict__ Aseg,
    const unsigned char* __restrict__ Bseg, int kt, int tid, int lane,
    int wm, int wn, frag8 (&ca)[4], frag8 (&cb)[2],
    frag8 (&na)[4], frag8 (&nb)[2], f32x16 (&acc)[4][2]) {
    // gate: own staging loads for tile kt+1 landed AND own ds_reads drained;
    // then barrier -> ALL waves' staging for tile kt+1 visible (cross-wave).
    if constexpr (VW == 4)
        asm volatile("s_waitcnt vmcnt(4) lgkmcnt(0)" ::: "memory");
    else if constexpr (VW == 0)
        asm volatile("s_waitcnt vmcnt(0) lgkmcnt(0)" ::: "memory");
    if constexpr (VW >= 0) {
        SB();
        __builtin_amdgcn_s_barrier();
        SB();
    }

    const unsigned char* nbuf = sbase + (size_t)((kt + 1) & 3) * 32768;
    const unsigned char* nAl = nbuf + wm * 4 * 2048 + lane * 16;
    const unsigned char* nBl = nbuf + 16384 + wn * 2 * 2048 + lane * 16;
    unsigned char* stbuf = sbase + (size_t)((kt + 3) & 3) * 32768;

    // ---- phase 0: reads A0,A1,B0 of kt+1 ; stages r0,r1 ; MFMA col 0 ----
    if constexpr (NEXT) {
        na[0].p.lo = *(const i32x4*)(nAl + 0 * 2048);
        na[0].p.hi = *(const i32x4*)(nAl + 0 * 2048 + 1024);
        na[1].p.lo = *(const i32x4*)(nAl + 1 * 2048);
        na[1].p.hi = *(const i32x4*)(nAl + 1 * 2048 + 1024);
        nb[0].p.lo = *(const i32x4*)(nBl);
        nb[0].p.hi = *(const i32x4*)(nBl + 1024);
    }
    if constexpr (STG) {
        stage_q(Aseg, Bseg, stbuf, tid, kt + 3, 0);
        stage_q(Aseg, Bseg, stbuf, tid, kt + 3, 1);
    }
    SB();
    __builtin_amdgcn_s_setprio(1);
#pragma unroll
    for (int i = 0; i < 4; ++i)
        acc[i][0] = __builtin_amdgcn_mfma_scale_f32_32x32x64_f8f6f4(
            ca[i].v, cb[0].v, acc[i][0],
            0, 0, 0, 0x7f7f7f7f, 0, 0x7f7f7f7f);
    __builtin_amdgcn_s_setprio(0);
    SB();
    __builtin_amdgcn_s_barrier();     // mid pacing barrier (uniform, data-free)
    SB();

    // ---- phase 1: reads A2,A3,B1 of kt+1 ; stages r2,r3 ; MFMA col 1 ----
    if constexpr (NEXT) {
        na[2].p.lo = *(const i32x4*)(nAl + 2 * 2048);
        na[2].p.hi = *(const i32x4*)(nAl + 2 * 2048 + 1024);
        na[3].p.lo = *(const i32x4*)(nAl + 3 * 2048);
        na[3].p.hi = *(const i32x4*)(nAl + 3 * 2048 + 1024);
        nb[1].p.lo = *(const i32x4*)(nBl + 2048);
        nb[1].p.hi = *(const i32x4*)(nBl + 2048 + 1024);
    }
    if constexpr (STG) {
        stage_q(Aseg, Bseg, stbuf, tid, kt + 3, 2);
        stage_q(Aseg, Bseg, stbuf, tid, kt + 3, 3);
    }
    SB();
    __builtin_amdgcn_s_setprio(1);
#pragma unroll
    for (int i = 0; i < 4; ++i)
        acc[i][1] = __builtin_amdgcn_mfma_scale_f32_32x32x64_f8f6f4(
            ca[i].v, cb[1].v, acc[i][1],
            0, 0, 0, 0x7f7f7f7f, 0, 0x7f7f7f7f);
    __builtin_amdgcn_s_setprio(0);
}

__global__ __launch_bounds__(512, 2) void gemm_fp8_kernel(
    const unsigned char* __restrict__ qa, const unsigned char* __restrict__ qw,
    float* __restrict__ out, const unsigned* __restrict__ amax) {
    __shared__ unsigned char lds[4][32768];   // 128 KB: 4 buffers (A 16K + B 16K)

    // XCD-bijective swizzle (nwg = 1024, divisible by 8)
    int b = blockIdx.x;
    int swz = (b & 7) * 128 + (b >> 3);
    int bm = swz >> 4;            // M/BM = 64 ; N/BN = 16
    int bn = swz & 15;

    int tid = threadIdx.x;
    int lane = tid & 63;
    int w = tid >> 6;
    int wm = w >> 2, wn = w & 3;  // 2x4 wave grid, wave tile 128x64

    f32x16 acc[4][2];
#pragma unroll
    for (int i = 0; i < 4; ++i)
#pragma unroll
        for (int j = 0; j < 2; ++j) acc[i][j] = (f32x16)0.f;

    const unsigned char* Aseg = qa + (long)(bm * 8) * NK64 * 2048;
    const unsigned char* Bseg = qw + (long)(bn * 8) * NK64 * 2048;
    unsigned char* sbase = &lds[0][0];

    frag8 A0[4], B0[2], A1[4], B1[2];

    // prologue: stage tiles 0,1,2 (depth-3)
#pragma unroll
    for (int pt = 0; pt < 3; ++pt)
#pragma unroll
        for (int r = 0; r < 4; ++r)
            stage_q(Aseg, Bseg, sbase + (size_t)pt * 32768, tid, pt, r);
    asm volatile("s_waitcnt vmcnt(0)" ::: "memory");   // all staged tiles resident
    SB();
    __builtin_amdgcn_s_barrier();                      // ..for all waves
    SB();
    {   // read tile-0 fragments
        const unsigned char* Al = sbase + wm * 4 * 2048 + lane * 16;
        const unsigned char* Bl = sbase + 16384 + wn * 2 * 2048 + lane * 16;
#pragma unroll
        for (int i = 0; i < 4; ++i) {
            A0[i].p.lo = *(const i32x4*)(Al + i * 2048);
            A0[i].p.hi = *(const i32x4*)(Al + i * 2048 + 1024);
        }
#pragma unroll
        for (int j = 0; j < 2; ++j) {
            B0[j].p.lo = *(const i32x4*)(Bl + j * 2048);
            B0[j].p.hi = *(const i32x4*)(Bl + j * 2048 + 1024);
        }
    }

    // step 0 (no gate): uses (A0,B0); reads tile-1 frags; stages tile 3
    tile_step<-1, true, true>(sbase, Aseg, Bseg, 0, tid, lane, wm, wn,
                              A0, B0, A1, B1, acc);
#pragma unroll 1
    for (int kt = 1; kt < 61; kt += 2) {   // covers kt = 1..60
        tile_step<4, true, true>(sbase, Aseg, Bseg, kt, tid, lane, wm, wn,
                                 A1, B1, A0, B0, acc);
        tile_step<4, true, true>(sbase, Aseg, Bseg, kt + 1, tid, lane, wm, wn,
                                 A0, B0, A1, B1, acc);
    }
    tile_step<4, false, true>(sbase, Aseg, Bseg, 61, tid, lane, wm, wn,
                              A1, B1, A0, B0, acc);
    tile_step<0, false, true>(sbase, Aseg, Bseg, 62, tid, lane, wm, wn,
                              A0, B0, A1, B1, acc);
    tile_step<-1, false, false>(sbase, Aseg, Bseg, 63, tid, lane, wm, wn,
                                A1, B1, A0, B0, acc);

    // epilogue: dequant scale = (amax_x/448) * (amax_w/448)
    float ax = fmaxf(__uint_as_float(amax[0]), 1e-12f);
    float aw = fmaxf(__uint_as_float(amax[1]), 1e-12f);
    float s = ax * aw * (1.0f / (FP8_MAX * FP8_MAX));

    long m0 = (long)bm * BM + wm * 128;
    long n0 = (long)bn * BN + wn * 64;
    int col = lane & 31;
    int rbase = 4 * (lane >> 5);
#pragma unroll
    for (int i = 0; i < 4; ++i)
#pragma unroll
        for (int j = 0; j < 2; ++j)
#pragma unroll
            for (int reg = 0; reg < 16; ++reg) {
                int row = (reg & 3) + 8 * (reg >> 2) + rbase;
                out[(m0 + i * 32 + row) * N_DIM + n0 + j * 32 + col] =
                    acc[i][j][reg] * s;
            }
}

extern "C" void kernel_launch(void* const* d_in, const int* in_sizes, int n_in,
                              void* d_out, int out_size, void* d_ws, size_t ws_size,
                              hipStream_t stream) {
    const float* x = (const float*)d_in[0];       // (8,2048,4096) = (M,K)
    const float* wgt = (const float*)d_in[1];     // (K,N)
    float* out = (float*)d_out;

    // workspace layout
    unsigned* amax = (unsigned*)d_ws;                         // 2 words
    unsigned char* qa = (unsigned char*)d_ws + 256;           // M*K fp8 = 64MB packed
    unsigned char* qw = qa + (long)M_DIM * K_DIM;             // N*K fp8 = 16MB packed

    hipMemsetAsync(amax, 0, 8, stream);   // replaces init kernel (capture-safe)
    amax2_kernel<<<3072, 256, 0, stream>>>(x, wgt, amax);
    quant_kernel<<<6144, 256, 0, stream>>>(x, wgt, qa, qw, amax);

    dim3 grid((M_DIM / BM) * (N_DIM / BN));  // 1024
    gemm_fp8_kernel<<<grid, 512, 0, stream>>>(qa, qw, out, amax);
}

// Round 18
// 420.050 us; speedup vs baseline: 1.0897x; 1.0125x over previous
//
#include <hip/hip_runtime.h>
#include <hip/hip_bf16.h>

#define M_DIM 16384
#define N_DIM 4096
#define K_DIM 4096
#define FP8_MAX 448.0f

#define BM 256
#define BN 256
#define NK64 (K_DIM / 64)   // 64 k64-blocks = K-tiles

typedef float f32x16 __attribute__((ext_vector_type(16)));
typedef int i32x4 __attribute__((ext_vector_type(4)));
typedef int i32x8 __attribute__((ext_vector_type(8)));

// 8-wide MFMA operand whose halves are filled directly by ds_read_b128.
typedef union {
    i32x8 v;
    struct { i32x4 lo, hi; } p;
} frag8;

// Packed fp8 operand layout (A and B identical), matched to the
// mfma_scale_f32_32x32x64_f8f6f4 fragment: lane l holds
//   row = row32*32 + (l&31),  k = k64*64 + (l>>5)*32 + h*16 + j  (h=0,1; j=0..15)
// stored as [row32-block][k64-block][h][lane][16B]  (block = 2048 B).
// GEMM = R17 (passing, ~250us) VERBATIM. This round: quant_x processes two
// k64-blocks per iteration (8 barriers not 16, uint4 stores not uint2).
// scales = 1.0 e8m0 -> bit-identical to plain fp8 GEMM math.

// ---------------- fused amax reduction (x then w) ----------------
__global__ void amax2_kernel(const float* __restrict__ x,
                             const float* __restrict__ w,
                             unsigned* __restrict__ amax) {
    const float* p;
    long n4;
    unsigned* out;
    long bid, nb;
    if (blockIdx.x < 2048) {
        p = x; n4 = (long)M_DIM * K_DIM / 4; out = amax + 0;
        bid = blockIdx.x; nb = 2048;
    } else {
        p = w; n4 = (long)K_DIM * N_DIM / 4; out = amax + 1;
        bid = blockIdx.x - 2048; nb = 1024;
    }
    float m = 0.f;
    const float4* p4 = (const float4*)p;
    for (long i = bid * blockDim.x + threadIdx.x; i < n4; i += nb * blockDim.x) {
        float4 v = p4[i];
        m = fmaxf(m, fmaxf(fmaxf(fabsf(v.x), fabsf(v.y)),
                           fmaxf(fabsf(v.z), fabsf(v.w))));
    }
#pragma unroll
    for (int off = 32; off > 0; off >>= 1)
        m = fmaxf(m, __shfl_down(m, off));
    __shared__ float smax[4];
    int lane = threadIdx.x & 63, wid = threadIdx.x >> 6;
    if (lane == 0) smax[wid] = m;
    __syncthreads();
    if (threadIdx.x == 0) {
        float bm = fmaxf(fmaxf(smax[0], smax[1]), fmaxf(smax[2], smax[3]));
        atomicMax(out, __float_as_uint(bm));  // positive floats: bit order == value order
    }
}

__device__ __forceinline__ unsigned pack4(float4 v, float s) {
    float a = fminf(fmaxf(v.x * s, -FP8_MAX), FP8_MAX);
    float b = fminf(fmaxf(v.y * s, -FP8_MAX), FP8_MAX);
    float c = fminf(fmaxf(v.z * s, -FP8_MAX), FP8_MAX);
    float d = fminf(fmaxf(v.w * s, -FP8_MAX), FP8_MAX);
    int p = 0;
    p = __builtin_amdgcn_cvt_pk_fp8_f32(a, b, p, false);
    p = __builtin_amdgcn_cvt_pk_fp8_f32(c, d, p, true);
    return (unsigned)p;
}

// -------- fused quantize: blocks 0..2047 -> x ; 2048..6143 -> weight --------
// x path: block = (m32, kq); 16 k64-blocks, TWO per iteration via a 4-buffer
// LDS bounce (pairs {0,1}/{2,3} alternate; 1 sync/iter is race-free since
// write(it+2) to a pair is ordered after all reads(it) by sync(it+1)).
//   read: t -> row t>>3, k-words (t&7)*2 (coalesced)
//   emit: t -> byte (t&127)*16 of block k64+(t>>7) (fully coalesced uint4)
__global__ void quant_kernel(const float* __restrict__ x,
                             const float* __restrict__ w,
                             unsigned char* __restrict__ qa,
                             unsigned char* __restrict__ qw,
                             const unsigned* __restrict__ amax) {
    __shared__ unsigned tile[4][32][17];  // x: 4 bounce buffers; wt: cast [64][17]
    int t = threadIdx.x;
    if (blockIdx.x < 2048) {
        // ---- x path: (M,K) fp32 -> packed fp8, coalesced via LDS ----
        float scale = FP8_MAX / fmaxf(__uint_as_float(amax[0]), 1e-12f);
        int m32 = blockIdx.x >> 2;        // 0..511
        int kq = blockIdx.x & 3;          // k-quarter: k64 in [kq*16, kq*16+16)
        int rin = t >> 3;                 // input row 0..31
        int win = (t & 7) * 2;            // input k-word pair
        const float* rp = x + (long)(m32 * 32 + rin) * K_DIM;
        unsigned char* ob = qa + (long)m32 * NK64 * 2048;
        // output: 16B chunk (t&127)*16 of block k64+(t>>7)
        int blk = t >> 7;                 // which k64 of the pair
        int rowo = t & 31;
        int kw0 = ((t >> 5) & 1) * 8 + ((t & 127) >> 6) * 4;
#pragma unroll
        for (int it = 0; it < 8; ++it) {
            int k64 = kq * 16 + it * 2;
            int pr = (it & 1) * 2;        // buffer pair {0,1} or {2,3}
            float4 va0 = *(const float4*)&rp[k64 * 64 + win * 4];
            float4 va1 = *(const float4*)&rp[k64 * 64 + win * 4 + 4];
            float4 vb0 = *(const float4*)&rp[(k64 + 1) * 64 + win * 4];
            float4 vb1 = *(const float4*)&rp[(k64 + 1) * 64 + win * 4 + 4];
            tile[pr][rin][win] = pack4(va0, scale);
            tile[pr][rin][win + 1] = pack4(va1, scale);
            tile[pr + 1][rin][win] = pack4(vb0, scale);
            tile[pr + 1][rin][win + 1] = pack4(vb1, scale);
            __syncthreads();
            const unsigned* tr = &tile[pr + blk][rowo][kw0];
            uint4 o;
            o.x = tr[0]; o.y = tr[1]; o.z = tr[2]; o.w = tr[3];
            *(uint4*)&ob[(long)(k64 + blk) * 2048 + (t & 127) * 16] = o;
        }
    } else {
        // ---- weight path: (K,N) -> packed fp8 (N-major) ----
        unsigned (*wt)[17] = (unsigned(*)[17])tile;   // [64][17] view
        float scale = FP8_MAX / fmaxf(__uint_as_float(amax[1]), 1e-12f);
        int b = blockIdx.x - 2048;        // 4096 = (K/64) * (N/64)
        int bk = b & 63, bn = b >> 6;
        int k0 = bk * 64, n0 = bn * 64;
#pragma unroll
        for (int pass = 0; pass < 4; ++pass) {
            int idx = pass * 256 + t;     // 64 k x 16 words
            int k = idx >> 4, nw = idx & 15;
            float4 v = *(const float4*)&w[(long)(k0 + k) * N_DIM + n0 + nw * 4];
            wt[k][nw] = pack4(v, scale);
        }
        __syncthreads();
        int lane = t & 63, g = t >> 6;
        int n32 = g >> 1, h = g & 1;      // 2 n32-blocks x 2 halves
        int nl = n32 * 32 + (lane & 31);
        int word = nl >> 2, sh = (nl & 3) * 8;
        int kb = (lane >> 5) * 32 + h * 16;
        uint4 o;
        unsigned* ow = (unsigned*)&o;
#pragma unroll
        for (int wd = 0; wd < 4; ++wd) {
            unsigned acc = 0;
#pragma unroll
            for (int j = 0; j < 4; ++j)
                acc |= ((wt[kb + wd * 4 + j][word] >> sh) & 0xffu) << (8 * j);
            ow[wd] = acc;
        }
        long gn32 = (long)(n0 >> 5) + n32;
        *(uint4*)&qw[(gn32 * NK64 + bk) * 2048 + h * 1024 + lane * 16] = o;
    }
}

// ---------------- MX-fp8 GEMM, 2-phase paced, reg-double-buffered ----------------
__device__ __forceinline__ void stage_q(const unsigned char* __restrict__ Aseg,
                                        const unsigned char* __restrict__ Bseg,
                                        unsigned char* stbuf, int tid, int kt, int r) {
    int c = r * 512 + tid;                // 0..2047: 1024 A chunks then 1024 B
    int f = (c >> 7) & 7;                 // row32-block 0..7
    int q = c & 127;
    const unsigned char* src =
        ((c < 1024) ? Aseg : Bseg) + ((long)f * NK64 + kt) * 2048 + q * 16;
    __builtin_amdgcn_global_load_lds(
        (const __attribute__((address_space(1))) void*)src,
        (__attribute__((address_space(3))) void*)(stbuf + c * 16), 16, 0, 0);
}

#define SB() __builtin_amdgcn_sched_barrier(0)

// One K-tile step. On entry: frags for tile kt live in (ca, cb).
template <int VW, bool STG, bool NEXT>
__device__ __forceinline__ void tile_step(
    unsigned char* sbase, const unsigned char* __restrict__ Aseg,
    const unsigned char* __restrict__ Bseg, int kt, int tid, int lane,
    int wm, int wn, frag8 (&ca)[4], frag8 (&cb)[2],
    frag8 (&na)[4], frag8 (&nb)[2], f32x16 (&acc)[4][2]) {
    // gate: own staging loads for tile kt+1 landed AND own ds_reads drained;
    // then barrier -> ALL waves' staging for tile kt+1 visible (cross-wave).
    if constexpr (VW == 4)
        asm volatile("s_waitcnt vmcnt(4) lgkmcnt(0)" ::: "memory");
    else if constexpr (VW == 0)
        asm volatile("s_waitcnt vmcnt(0) lgkmcnt(0)" ::: "memory");
    if constexpr (VW >= 0) {
        SB();
        __builtin_amdgcn_s_barrier();
        SB();
    }

    const unsigned char* nbuf = sbase + (size_t)((kt + 1) & 3) * 32768;
    const unsigned char* nAl = nbuf + wm * 4 * 2048 + lane * 16;
    const unsigned char* nBl = nbuf + 16384 + wn * 2 * 2048 + lane * 16;
    unsigned char* stbuf = sbase + (size_t)((kt + 3) & 3) * 32768;

    // ---- phase 0: reads A0,A1,B0 of kt+1 ; stages r0,r1 ; MFMA col 0 ----
    if constexpr (NEXT) {
        na[0].p.lo = *(const i32x4*)(nAl + 0 * 2048);
        na[0].p.hi = *(const i32x4*)(nAl + 0 * 2048 + 1024);
        na[1].p.lo = *(const i32x4*)(nAl + 1 * 2048);
        na[1].p.hi = *(const i32x4*)(nAl + 1 * 2048 + 1024);
        nb[0].p.lo = *(const i32x4*)(nBl);
        nb[0].p.hi = *(const i32x4*)(nBl + 1024);
    }
    if constexpr (STG) {
        stage_q(Aseg, Bseg, stbuf, tid, kt + 3, 0);
        stage_q(Aseg, Bseg, stbuf, tid, kt + 3, 1);
    }
    SB();
    __builtin_amdgcn_s_setprio(1);
#pragma unroll
    for (int i = 0; i < 4; ++i)
        acc[i][0] = __builtin_amdgcn_mfma_scale_f32_32x32x64_f8f6f4(
            ca[i].v, cb[0].v, acc[i][0],
            0, 0, 0, 0x7f7f7f7f, 0, 0x7f7f7f7f);
    __builtin_amdgcn_s_setprio(0);
    SB();
    __builtin_amdgcn_s_barrier();     // mid pacing barrier (uniform, data-free)
    SB();

    // ---- phase 1: reads A2,A3,B1 of kt+1 ; stages r2,r3 ; MFMA col 1 ----
    if constexpr (NEXT) {
        na[2].p.lo = *(const i32x4*)(nAl + 2 * 2048);
        na[2].p.hi = *(const i32x4*)(nAl + 2 * 2048 + 1024);
        na[3].p.lo = *(const i32x4*)(nAl + 3 * 2048);
        na[3].p.hi = *(const i32x4*)(nAl + 3 * 2048 + 1024);
        nb[1].p.lo = *(const i32x4*)(nBl + 2048);
        nb[1].p.hi = *(const i32x4*)(nBl + 2048 + 1024);
    }
    if constexpr (STG) {
        stage_q(Aseg, Bseg, stbuf, tid, kt + 3, 2);
        stage_q(Aseg, Bseg, stbuf, tid, kt + 3, 3);
    }
    SB();
    __builtin_amdgcn_s_setprio(1);
#pragma unroll
    for (int i = 0; i < 4; ++i)
        acc[i][1] = __builtin_amdgcn_mfma_scale_f32_32x32x64_f8f6f4(
            ca[i].v, cb[1].v, acc[i][1],
            0, 0, 0, 0x7f7f7f7f, 0, 0x7f7f7f7f);
    __builtin_amdgcn_s_setprio(0);
}

__global__ __launch_bounds__(512, 2) void gemm_fp8_kernel(
    const unsigned char* __restrict__ qa, const unsigned char* __restrict__ qw,
    float* __restrict__ out, const unsigned* __restrict__ amax) {
    __shared__ unsigned char lds[4][32768];   // 128 KB: 4 buffers (A 16K + B 16K)

    // XCD-bijective swizzle (nwg = 1024, divisible by 8)
    int b = blockIdx.x;
    int swz = (b & 7) * 128 + (b >> 3);
    int bm = swz >> 4;            // M/BM = 64 ; N/BN = 16
    int bn = swz & 15;

    int tid = threadIdx.x;
    int lane = tid & 63;
    int w = tid >> 6;
    int wm = w >> 2, wn = w & 3;  // 2x4 wave grid, wave tile 128x64

    f32x16 acc[4][2];
#pragma unroll
    for (int i = 0; i < 4; ++i)
#pragma unroll
        for (int j = 0; j < 2; ++j) acc[i][j] = (f32x16)0.f;

    const unsigned char* Aseg = qa + (long)(bm * 8) * NK64 * 2048;
    const unsigned char* Bseg = qw + (long)(bn * 8) * NK64 * 2048;
    unsigned char* sbase = &lds[0][0];

    frag8 A0[4], B0[2], A1[4], B1[2];

    // prologue: stage tiles 0,1,2 (depth-3)
#pragma unroll
    for (int pt = 0; pt < 3; ++pt)
#pragma unroll
        for (int r = 0; r < 4; ++r)
            stage_q(Aseg, Bseg, sbase + (size_t)pt * 32768, tid, pt, r);
    asm volatile("s_waitcnt vmcnt(0)" ::: "memory");   // all staged tiles resident
    SB();
    __builtin_amdgcn_s_barrier();                      // ..for all waves
    SB();
    {   // read tile-0 fragments
        const unsigned char* Al = sbase + wm * 4 * 2048 + lane * 16;
        const unsigned char* Bl = sbase + 16384 + wn * 2 * 2048 + lane * 16;
#pragma unroll
        for (int i = 0; i < 4; ++i) {
            A0[i].p.lo = *(const i32x4*)(Al + i * 2048);
            A0[i].p.hi = *(const i32x4*)(Al + i * 2048 + 1024);
        }
#pragma unroll
        for (int j = 0; j < 2; ++j) {
            B0[j].p.lo = *(const i32x4*)(Bl + j * 2048);
            B0[j].p.hi = *(const i32x4*)(Bl + j * 2048 + 1024);
        }
    }

    // step 0 (no gate): uses (A0,B0); reads tile-1 frags; stages tile 3
    tile_step<-1, true, true>(sbase, Aseg, Bseg, 0, tid, lane, wm, wn,
                              A0, B0, A1, B1, acc);
#pragma unroll 1
    for (int kt = 1; kt < 61; kt += 2) {   // covers kt = 1..60
        tile_step<4, true, true>(sbase, Aseg, Bseg, kt, tid, lane, wm, wn,
                                 A1, B1, A0, B0, acc);
        tile_step<4, true, true>(sbase, Aseg, Bseg, kt + 1, tid, lane, wm, wn,
                                 A0, B0, A1, B1, acc);
    }
    tile_step<4, false, true>(sbase, Aseg, Bseg, 61, tid, lane, wm, wn,
                              A1, B1, A0, B0, acc);
    tile_step<0, false, true>(sbase, Aseg, Bseg, 62, tid, lane, wm, wn,
                              A0, B0, A1, B1, acc);
    tile_step<-1, false, false>(sbase, Aseg, Bseg, 63, tid, lane, wm, wn,
                                A1, B1, A0, B0, acc);

    // epilogue: dequant scale = (amax_x/448) * (amax_w/448)
    float ax = fmaxf(__uint_as_float(amax[0]), 1e-12f);
    float aw = fmaxf(__uint_as_float(amax[1]), 1e-12f);
    float s = ax * aw * (1.0f / (FP8_MAX * FP8_MAX));

    long m0 = (long)bm * BM + wm * 128;
    long n0 = (long)bn * BN + wn * 64;
    int col = lane & 31;
    int rbase = 4 * (lane >> 5);
#pragma unroll
    for (int i = 0; i < 4; ++i)
#pragma unroll
        for (int j = 0; j < 2; ++j)
#pragma unroll
            for (int reg = 0; reg < 16; ++reg) {
                int row = (reg & 3) + 8 * (reg >> 2) + rbase;
                out[(m0 + i * 32 + row) * N_DIM + n0 + j * 32 + col] =
                    acc[i][j][reg] * s;
            }
}

extern "C" void kernel_launch(void* const* d_in, const int* in_sizes, int n_in,
                              void* d_out, int out_size, void* d_ws, size_t ws_size,
                              hipStream_t stream) {
    const float* x = (const float*)d_in[0];       // (8,2048,4096) = (M,K)
    const float* wgt = (const float*)d_in[1];     // (K,N)
    float* out = (float*)d_out;

    // workspace layout
    unsigned* amax = (unsigned*)d_ws;                         // 2 words
    unsigned char* qa = (unsigned char*)d_ws + 256;           // M*K fp8 = 64MB packed
    unsigned char* qw = qa + (long)M_DIM * K_DIM;             // N*K fp8 = 16MB packed

    hipMemsetAsync(amax, 0, 8, stream);   // capture-safe zero-init
    amax2_kernel<<<3072, 256, 0, stream>>>(x, wgt, amax);
    quant_kernel<<<6144, 256, 0, stream>>>(x, wgt, qa, qw, amax);

    dim3 grid((M_DIM / BM) * (N_DIM / BN));  // 1024
    gemm_fp8_kernel<<<grid, 512, 0, stream>>>(qa, qw, out, amax);
}